// Round 10
// baseline (197.130 us; speedup 1.0000x reference)
//
#include <hip/hip_runtime.h>
#include <hip/hip_bf16.h>
#include <math.h>
#include <stdint.h>

// Problem constants
#define N_ROWS 4096
#define IN_F   1024
#define HEAD_N 4002
#define C0_H   256
#define C0_N   16000
#define C1_H   64
#define C1_N   30257
#define CUT0   4000
#define CUT1   20000
#define HW1    384     // packed hidden width: 256 (c0) + 128 (c1 padded)

#define LOG2E 1.4426950408889634f
#define LN2   0.6931471805599453f

typedef __attribute__((ext_vector_type(8))) short bf16x8;
typedef __attribute__((ext_vector_type(4))) float f32x4;

__device__ __forceinline__ float exp2_fast(float x) {
    return __builtin_amdgcn_exp2f(x);   // v_exp_f32 (hardware exp2)
}

__device__ __forceinline__ ushort f2bf(float f) {
    uint32_t u = __builtin_bit_cast(uint32_t, f);
    uint32_t r = (u + 0x7fffu + ((u >> 16) & 1u)) >> 16;
    return (ushort)r;
}
__device__ __forceinline__ float bf2f(ushort u) {
    return __builtin_bit_cast(float, (uint32_t)u << 16);
}

__device__ __forceinline__ void gload_lds_16(const void* gsrc, void* ldst) {
    __builtin_amdgcn_global_load_lds(
        (const __attribute__((address_space(1))) void*)(uintptr_t)gsrc,
        (__attribute__((address_space(3))) void*)(uint32_t)(uintptr_t)ldst,
        16, 0, 0);
}

// ---------- casts ----------
__global__ __launch_bounds__(256)
void cast_f32_bf16(const float* __restrict__ in, ushort* __restrict__ out, int n)
{
    int i = (blockIdx.x * 256 + threadIdx.x) * 4;
    if (i >= n) return;
    float4 v = *reinterpret_cast<const float4*>(in + i);
    ushort4 o;
    o.x = f2bf(v.x); o.y = f2bf(v.y); o.z = f2bf(v.z); o.w = f2bf(v.w);
    *reinterpret_cast<ushort4*>(out + i) = o;
}

// B fp32 [K,N] -> BT bf16 [Npad,K] (scaled), pad rows zeroed.
// grid (Npad/32, K/32), block (32,8)
__global__ __launch_bounds__(256)
void castT(const float* __restrict__ B, ushort* __restrict__ BT, int K, int N,
           float scale)
{
    __shared__ float t[32][33];
    const int tx = threadIdx.x, ty = threadIdx.y;
    const int n0 = blockIdx.x * 32, k0 = blockIdx.y * 32;
    #pragma unroll
    for (int i = 0; i < 4; ++i) {
        int n = n0 + tx;
        t[ty + i * 8][tx] = (n < N) ? B[(size_t)(k0 + ty + i * 8) * N + n] : 0.0f;
    }
    __syncthreads();
    #pragma unroll
    for (int i = 0; i < 4; ++i) {
        int n = n0 + ty + i * 8;
        BT[(size_t)n * K + k0 + tx] = f2bf(t[tx][ty + i * 8] * scale);
    }
}

// ---------- plain GEMM (bf16 out) for hidden projections (m97 structure) ----------
__global__ __launch_bounds__(256)
void gemm_out(const ushort* __restrict__ A, int lda,
              const ushort* __restrict__ BT, int ldb, int K,
              int Nreal, ushort* __restrict__ Cout, int ldc)
{
    __shared__ ushort As[128 * 32];
    __shared__ ushort Bs[128 * 32];
    const int tid = threadIdx.x;
    const int l = tid & 63, w = tid >> 6;
    const int rowBase = blockIdx.y * 128, colBase = blockIdx.x * 128;
    const int rsel = l & 15, ksel = l >> 4;
    const int sr = l >> 2, skq = (l & 3) * 8;

    f32x4 acc[2][8];
    #pragma unroll
    for (int mi = 0; mi < 2; ++mi)
        #pragma unroll
        for (int ni = 0; ni < 8; ++ni) acc[mi][ni] = (f32x4){0.f, 0.f, 0.f, 0.f};

    for (int k0 = 0; k0 < K; k0 += 32) {
        #pragma unroll
        for (int i = 0; i < 2; ++i) {
            const int c = w + i * 4;
            gload_lds_16(A + (size_t)(rowBase + c * 16 + sr) * lda + k0 + skq,
                         (char*)As + c * 1024);
            gload_lds_16(BT + (size_t)(colBase + c * 16 + sr) * ldb + k0 + skq,
                         (char*)Bs + c * 1024);
        }
        __syncthreads();
        bf16x8 af[2], bfr[8];
        #pragma unroll
        for (int mi = 0; mi < 2; ++mi)
            af[mi] = *reinterpret_cast<const bf16x8*>(As + (w * 32 + mi * 16 + rsel) * 32 + ksel * 8);
        #pragma unroll
        for (int ni = 0; ni < 8; ++ni)
            bfr[ni] = *reinterpret_cast<const bf16x8*>(Bs + (ni * 16 + rsel) * 32 + ksel * 8);
        #pragma unroll
        for (int mi = 0; mi < 2; ++mi)
            #pragma unroll
            for (int ni = 0; ni < 8; ++ni)
                acc[mi][ni] = __builtin_amdgcn_mfma_f32_16x16x32_bf16(af[mi], bfr[ni], acc[mi][ni], 0, 0, 0);
        __syncthreads();
    }
    #pragma unroll
    for (int mi = 0; mi < 2; ++mi)
        #pragma unroll
        for (int ni = 0; ni < 8; ++ni) {
            const int col = colBase + ni * 16 + rsel;
            if (col < Nreal) {
                #pragma unroll
                for (int j = 0; j < 4; ++j) {
                    const int row = rowBase + w * 32 + mi * 16 + ksel * 4 + j;
                    Cout[(size_t)row * ldc + col] = f2bf(acc[mi][ni][j]);
                }
            }
        }
}

// ---------- pipelined streaming sum-exp2 GEMM, fat-wave 16x16x32 ----------
// Block tile 128 rows x 256 cols x BK=32. 4 waves in a 2x2 grid: wave w ->
// rows (w>>1)*64, cols (w&1)*128 (Mrep=4 x Nrep=8 of 16x16x32). 12
// ds_read_b128 per 32 MFMAs. LDS 48 KB dbuf, depth-2 counted vmcnt(6), raw
// s_barrier. Waves sharing rows combine their half-tile row-sums via LDS
// before the ps write (no write race). B pre-scaled by log2e -> bare
// v_exp_f32. XCD-bijective 1-D grid decode (NS % 8 == 0).
__global__ __launch_bounds__(256, 2)
void sumexp_pipe(const ushort* __restrict__ A, int lda,
                 const ushort* __restrict__ BT, int ldb,
                 int K, int nCT, int ntiles, int Nreal,
                 float* __restrict__ ps, int nsplit)
{
    __shared__ ushort As[2][128 * 32];   // 2 x 8 KB
    __shared__ ushort Bs[2][256 * 32];   // 2 x 16 KB
    __shared__ float sred[128];          // cross-wave row-sum combine

    const int id = blockIdx.x;
    const int xsplit = ((id >> 8) << 3) + (id & 7);   // same xsplit -> same XCD
    const int yrow   = (id & 255) >> 3;

    const int tid = threadIdx.x;
    const int l = tid & 63, w = tid >> 6;
    const int rowBase = yrow * 128;
    const int rsel = l & 15, ksel = l >> 4;

    const int kchunks = K >> 5;                 // K/32
    const int ct0 = xsplit * ntiles;
    const int ctn = min(ntiles, nCT - ct0);
    const int nch = ctn * kchunks;

    // Staging: 1 KB piece = 16 rows x 32 k. Lane l -> row l>>2, slot (l&3);
    // source element offset pre-swizzled with ((row&3)<<4) bytes so that
    // LDS[row][byte b] = global[row][b ^ ((row&3)<<4)].
    const int srow = l >> 2;
    const int skq = ((((l & 3) << 4) ^ ((srow & 3) << 4)) >> 1);

    // Wave w: rows (w>>1)*64 .. +63, cols (w&1)*128 .. +127 of block tile.
    const int wrow = (w >> 1) * 64;
    const int wcol = (w & 1) * 128;
    // Read offset in a row (ushort units): swizzle cancels store swizzle.
    const int koff = (ksel * 8) ^ ((rsel & 3) << 3);

    f32x4 acc[4][8];
    float s_run[4][4];
    #pragma unroll
    for (int mi = 0; mi < 4; ++mi)
        #pragma unroll
        for (int j = 0; j < 4; ++j) s_run[mi][j] = 0.f;

    int i_kh = 0, i_ct = 0, issued = 0;
    #define ISSUE()                                                            \
    do {                                                                       \
        const int buf = issued & 1;                                            \
        const int k0 = i_kh << 5;                                              \
        const size_t cb = (size_t)(ct0 + i_ct) << 8;                           \
        _Pragma("unroll")                                                      \
        for (int i = 0; i < 2; ++i) {  /* A: 8 pieces, wave w -> 2w,2w+1 */    \
            const int c = w * 2 + i;                                           \
            gload_lds_16(A + (size_t)(rowBase + c * 16 + srow) * lda + k0 + skq,\
                         (char*)&As[buf][0] + c * 1024);                       \
        }                                                                      \
        _Pragma("unroll")                                                      \
        for (int i = 0; i < 4; ++i) {  /* B: 16 pieces, wave w -> 4w..4w+3 */  \
            const int c = w * 4 + i;                                           \
            gload_lds_16(BT + (cb + c * 16 + srow) * ldb + k0 + skq,           \
                         (char*)&Bs[buf][0] + c * 1024);                       \
        }                                                                      \
        ++issued;                                                              \
        if (++i_kh == kchunks) { i_kh = 0; ++i_ct; }                           \
    } while (0)

    ISSUE();
    if (nch > 1) ISSUE();

    int c_kh = 0;
    int c_colBase = ct0 << 8;

    for (int ch = 0; ch < nch; ++ch) {
        // Wait for chunk ch's 6 loads; leave ch+1's 6 in flight.
        if (ch + 1 < nch) asm volatile("s_waitcnt vmcnt(6)" ::: "memory");
        else              asm volatile("s_waitcnt vmcnt(0)" ::: "memory");
        __builtin_amdgcn_s_barrier();

        if (c_kh == 0) {
            #pragma unroll
            for (int mi = 0; mi < 4; ++mi)
                #pragma unroll
                for (int ni = 0; ni < 8; ++ni)
                    acc[mi][ni] = (f32x4){0.f, 0.f, 0.f, 0.f};
        }

        const int buf = ch & 1;
        bf16x8 af[4], bfr[8];
        #pragma unroll
        for (int mi = 0; mi < 4; ++mi)
            af[mi] = *reinterpret_cast<const bf16x8*>(
                &As[buf][(wrow + mi * 16 + rsel) * 32 + koff]);
        #pragma unroll
        for (int ni = 0; ni < 8; ++ni)
            bfr[ni] = *reinterpret_cast<const bf16x8*>(
                &Bs[buf][(wcol + ni * 16 + rsel) * 32 + koff]);
        #pragma unroll
        for (int mi = 0; mi < 4; ++mi)
            #pragma unroll
            for (int ni = 0; ni < 8; ++ni)
                acc[mi][ni] = __builtin_amdgcn_mfma_f32_16x16x32_bf16(
                    af[mi], bfr[ni], acc[mi][ni], 0, 0, 0);

        __builtin_amdgcn_s_barrier();
        if (issued < nch) ISSUE();

        // Tile finished -> exp2-accumulate (registers only; overlaps prefetch)
        if (c_kh == kchunks - 1) {
            const int cbase = c_colBase + wcol;
            if (cbase + 128 > Nreal) {
                #pragma unroll
                for (int ni = 0; ni < 8; ++ni) {
                    const bool ok = (cbase + ni * 16 + rsel) < Nreal;
                    #pragma unroll
                    for (int mi = 0; mi < 4; ++mi)
                        #pragma unroll
                        for (int j = 0; j < 4; ++j)
                            s_run[mi][j] += ok ? exp2_fast(acc[mi][ni][j]) : 0.f;
                }
            } else {
                #pragma unroll
                for (int mi = 0; mi < 4; ++mi)
                    #pragma unroll
                    for (int ni = 0; ni < 8; ++ni)
                        #pragma unroll
                        for (int j = 0; j < 4; ++j)
                            s_run[mi][j] += exp2_fast(acc[mi][ni][j]);
            }
            c_kh = 0;
            c_colBase += 256;
        } else {
            ++c_kh;
        }
    }
    #undef ISSUE

    // Reduce over the 16 rsel lanes -> per-row half-tile sums. Waves sharing
    // rows (w&1==0 with w&1==1) combine via LDS; only w&1==0 writes ps.
    #pragma unroll
    for (int mi = 0; mi < 4; ++mi)
        #pragma unroll
        for (int j = 0; j < 4; ++j) {
            float S = s_run[mi][j];
            #pragma unroll
            for (int off = 8; off; off >>= 1) S += __shfl_xor(S, off);
            s_run[mi][j] = S;
            if ((w & 1) == 1 && rsel == 0)
                sred[wrow + mi * 16 + ksel * 4 + j] = S;
        }
    __syncthreads();
    if ((w & 1) == 0 && rsel == 0) {
        #pragma unroll
        for (int mi = 0; mi < 4; ++mi)
            #pragma unroll
            for (int j = 0; j < 4; ++j) {
                const int lrow = wrow + mi * 16 + ksel * 4 + j;
                ps[(size_t)(rowBase + lrow) * nsplit + xsplit] =
                    s_run[mi][j] + sred[lrow];
            }
    }
}

// ---------- target gather: one wave per row (weights pre-scaled by log2e) ----------
__global__ __launch_bounds__(256)
void gather_dot(const ushort* __restrict__ x_bf,
                const ushort* __restrict__ h_comb,
                const ushort* __restrict__ headWT,
                const ushort* __restrict__ t0W2T,
                const ushort* __restrict__ t1W2T,
                const int* __restrict__ target,
                float* __restrict__ pk_h, float* __restrict__ pk_c)
{
    const int r = blockIdx.x * 4 + (threadIdx.x >> 6);
    const int l = threadIdx.x & 63;
    const int t = target[r];

    const int gh = (t < CUT0) ? t : ((t < CUT1) ? CUT0 : CUT0 + 1);
    const ushort* xr = x_bf + (size_t)r * IN_F + l * 16;
    const ushort* wr = headWT + (size_t)gh * IN_F + l * 16;
    float s = 0.f;
    #pragma unroll
    for (int v = 0; v < 2; ++v) {
        ushort4 xa = *reinterpret_cast<const ushort4*>(xr + v * 8);
        ushort4 xb = *reinterpret_cast<const ushort4*>(xr + v * 8 + 4);
        ushort4 wa = *reinterpret_cast<const ushort4*>(wr + v * 8);
        ushort4 wb = *reinterpret_cast<const ushort4*>(wr + v * 8 + 4);
        s += bf2f(xa.x) * bf2f(wa.x) + bf2f(xa.y) * bf2f(wa.y)
           + bf2f(xa.z) * bf2f(wa.z) + bf2f(xa.w) * bf2f(wa.w)
           + bf2f(xb.x) * bf2f(wb.x) + bf2f(xb.y) * bf2f(wb.y)
           + bf2f(xb.z) * bf2f(wb.z) + bf2f(xb.w) * bf2f(wb.w);
    }
    #pragma unroll
    for (int off = 32; off; off >>= 1) s += __shfl_xor(s, off);
    if (l == 0) pk_h[r] = s * LN2;

    if (t >= CUT0) {
        float c = 0.f;
        if (t < CUT1) {
            const ushort* hr = h_comb + (size_t)r * HW1 + l * 4;
            const ushort* vr = t0W2T + (size_t)(t - CUT0) * C0_H + l * 4;
            ushort4 ha = *reinterpret_cast<const ushort4*>(hr);
            ushort4 va = *reinterpret_cast<const ushort4*>(vr);
            c = bf2f(ha.x) * bf2f(va.x) + bf2f(ha.y) * bf2f(va.y)
              + bf2f(ha.z) * bf2f(va.z) + bf2f(ha.w) * bf2f(va.w);
        } else {
            c = bf2f(h_comb[(size_t)r * HW1 + C0_H + l]) *
                bf2f(t1W2T[(size_t)(t - CUT1) * C1_H + l]);
        }
        #pragma unroll
        for (int off = 32; off; off >>= 1) c += __shfl_xor(c, off);
        if (l == 0) pk_c[r] = c * LN2;
    }
}

// ---------- combine: one thread per row ----------
__global__ __launch_bounds__(256)
void combine_rows(const float* __restrict__ ps_h, const float* __restrict__ ps_0,
                  const float* __restrict__ ps_1,
                  const float* __restrict__ pk_h, const float* __restrict__ pk_c,
                  const int* __restrict__ target, float* __restrict__ out,
                  int ns_h, int ns_0, int ns_1)
{
    const int r = blockIdx.x * 256 + threadIdx.x;
    if (r >= N_ROWS) return;
    float S = 0.f;
    const float* p = ps_h + (size_t)r * ns_h;
    for (int i = 0; i < ns_h; ++i) S += p[i];
    float o = pk_h[r] - __logf(S);
    const int t = target[r];
    if (t >= CUT0) {
        const float* q; int n;
        if (t < CUT1) { q = ps_0 + (size_t)r * ns_0; n = ns_0; }
        else          { q = ps_1 + (size_t)r * ns_1; n = ns_1; }
        float S2 = 0.f;
        for (int i = 0; i < n; ++i) S2 += q[i];
        o += pk_c[r] - __logf(S2);
    }
    out[r] = o;
}

__global__ __launch_bounds__(256)
void finalize_loss(const float* __restrict__ out, float* __restrict__ loss)
{
    float s = 0.f;
    for (int r = threadIdx.x; r < N_ROWS; r += 256) s += out[r];
    #pragma unroll
    for (int off = 32; off; off >>= 1) s += __shfl_xor(s, off);
    __shared__ float red[4];
    if ((threadIdx.x & 63) == 0) red[threadIdx.x >> 6] = s;
    __syncthreads();
    if (threadIdx.x == 0)
        loss[0] = -(red[0] + red[1] + red[2] + red[3]) / (float)N_ROWS;
}

extern "C" void kernel_launch(void* const* d_in, const int* in_sizes, int n_in,
                              void* d_out, int out_size, void* d_ws, size_t ws_size,
                              hipStream_t stream)
{
    const float* x      = (const float*)d_in[0];
    const int*   target = (const int*)  d_in[1];
    const float* head_W = (const float*)d_in[2];
    const float* t0_W1  = (const float*)d_in[3];
    const float* t0_W2  = (const float*)d_in[4];
    const float* t1_W1  = (const float*)d_in[5];
    const float* t1_W2  = (const float*)d_in[6];
    float* out = (float*)d_out;

    // Padded col counts (multiples of 256 for the 128x256 tile)
    const int HPAD  = 4096;    // head 4002 -> 16 tiles
    const int C0PAD = 16128;   // 63 tiles
    const int C1PAD = 30464;   // 119 tiles
    const int nCT_h = HPAD / 256;    // 16
    const int nCT_0 = C0PAD / 256;   // 63
    const int nCT_1 = C1PAD / 256;   // 119

    // 256-col tiles per block / col-splits; NS % 8 == 0 for XCD decode
    const int NT_H = 2,  NS_H = 8;    // 8*2  >= 16
    const int NT_0 = 4,  NS_0 = 16;   // 16*4 >= 63
    const int NT_1 = 5,  NS_1 = 24;   // 24*5 >= 119

    ushort* us = (ushort*)d_ws;
    ushort* x_bf   = us; us += (size_t)N_ROWS * IN_F;
    ushort* headWT = us; us += (size_t)HPAD * IN_F;
    ushort* hW1T   = us; us += (size_t)HW1 * IN_F;
    ushort* t0W2T  = us; us += (size_t)C0PAD * C0_H;
    ushort* t1W2T  = us; us += (size_t)C1PAD * C1_H;
    ushort* h_comb = us; us += (size_t)N_ROWS * HW1;

    float* ws   = (float*)us;
    float* ps_h = ws; ws += (size_t)N_ROWS * NS_H;
    float* ps_0 = ws; ws += (size_t)N_ROWS * NS_0;
    float* ps_1 = ws; ws += (size_t)N_ROWS * NS_1;
    float* pk_h = ws; ws += N_ROWS;
    float* pk_c = ws; ws += N_ROWS;

    const dim3 blk(256);

    // Casts / transposes (sum-exp B matrices pre-scaled by log2e)
    hipLaunchKernelGGL(cast_f32_bf16, dim3(N_ROWS * IN_F / 1024), blk, 0, stream,
                       x, x_bf, N_ROWS * IN_F);
    hipLaunchKernelGGL(castT, dim3(HPAD / 32, IN_F / 32), dim3(32, 8), 0, stream,
                       head_W, headWT, IN_F, HEAD_N, LOG2E);
    hipLaunchKernelGGL(castT, dim3(C0_H / 32, IN_F / 32), dim3(32, 8), 0, stream,
                       t0_W1, hW1T, IN_F, C0_H, 1.0f);
    hipLaunchKernelGGL(castT, dim3(128 / 32, IN_F / 32), dim3(32, 8), 0, stream,
                       t1_W1, hW1T + (size_t)C0_H * IN_F, IN_F, C1_H, 1.0f);
    hipLaunchKernelGGL(castT, dim3(C0PAD / 32, C0_H / 32), dim3(32, 8), 0, stream,
                       t0_W2, t0W2T, C0_H, C0_N, LOG2E);
    hipLaunchKernelGGL(castT, dim3(C1PAD / 32, C1_H / 32), dim3(32, 8), 0, stream,
                       t1_W2, t1W2T, C1_H, C1_N, LOG2E);

    // Packed hidden projections: h_comb[:, :320] = x @ [t0_W1 | t1_W1]
    hipLaunchKernelGGL(gemm_out, dim3(HW1 / 128, N_ROWS / 128), blk, 0, stream,
                       x_bf, IN_F, hW1T, IN_F, IN_F, C0_H + C1_H, h_comb, HW1);

    // Pipelined sum-exp2 GEMMs (1-D grids, XCD-bijective decode inside)
    hipLaunchKernelGGL(sumexp_pipe, dim3(NS_H * 32), blk, 0, stream,
                       x_bf, IN_F, headWT, IN_F, IN_F, nCT_h, NT_H, HEAD_N, ps_h, NS_H);
    hipLaunchKernelGGL(sumexp_pipe, dim3(NS_0 * 32), blk, 0, stream,
                       h_comb, HW1, t0W2T, C0_H, C0_H, nCT_0, NT_0, C0_N, ps_0, NS_0);
    hipLaunchKernelGGL(sumexp_pipe, dim3(NS_1 * 32), blk, 0, stream,
                       h_comb + C0_H, HW1, t1W2T, C1_H, C1_H, nCT_1, NT_1, C1_N, ps_1, NS_1);

    // Target gather + combine + loss
    hipLaunchKernelGGL(gather_dot, dim3(N_ROWS / 4), blk, 0, stream,
                       x_bf, h_comb, headWT, t0W2T, t1W2T, target, pk_h, pk_c);
    hipLaunchKernelGGL(combine_rows, dim3(N_ROWS / 256), blk, 0, stream,
                       ps_h, ps_0, ps_1, pk_h, pk_c, target, out, NS_H, NS_0, NS_1);
    hipLaunchKernelGGL(finalize_loss, dim3(1), blk, 0, stream, out, out + N_ROWS);
}